// Round 1
// 367.202 us; speedup vs baseline: 1.0511x; 1.0511x over previous
//
#include <hip/hip_runtime.h>

typedef __bf16 bf16x8 __attribute__((ext_vector_type(8)));
typedef float f32x4 __attribute__((ext_vector_type(4)));

#define MFMA16(a, b, c) __builtin_amdgcn_mfma_f32_16x16x32_bf16((a), (b), (c), 0, 0, 0)

__device__ __forceinline__ unsigned short f2bf(float f) {
    union { float f; unsigned int u; } v;
    v.f = f;
    unsigned int r = v.u + 0x7fffu + ((v.u >> 16) & 1u);
    return (unsigned short)(r >> 16);
}

// ---------------------------------------------------------------------------
// prep = cvt_weights + pe_bias merged (one launch).
// All 256 blocks convert the four 256x256 fp32 weight mats to bf16.
// Blocks 0..63 additionally compute the PE-folded q/k biases, stored
// TRANSPOSED: qpeT[ch][tok] (fused_attn now consumes [ch][tok]).
__global__ __launch_bounds__(256) void prep(
    const float* __restrict__ Wq, const float* __restrict__ bq,
    const float* __restrict__ Wk, const float* __restrict__ bk,
    const float* __restrict__ Wv, const float* __restrict__ Wp,
    unsigned short* __restrict__ Wbf,
    float* __restrict__ qpeT, float* __restrict__ kpeT)
{
    const int tid = threadIdx.x;
    {
        int i = blockIdx.x * 256 + tid;
        Wbf[i]          = f2bf(Wq[i]);
        Wbf[65536 + i]  = f2bf(Wk[i]);
        Wbf[131072 + i] = f2bf(Wv[i]);
        Wbf[196608 + i] = f2bf(Wp[i]);
    }
    if (blockIdx.x >= 64) return;

    __shared__ float pet[8 * 264];
    for (int t = tid; t < 8 * 256; t += 256) {
        int v = t >> 8, k = t & 255;
        float ang = 3.14f * (float)v * (float)(k & 63) * 0.005f;
        pet[v * 264 + k] = (k & 64) ? __cosf(ang) : __sinf(ang);
    }
    __syncthreads();

    const int p = tid & 63;                      // window position
    const int c = blockIdx.x * 4 + (tid >> 6);   // channel (wave-uniform)
    const int jx = p & 7, iy = p >> 3;
    const float4* rq4 = (const float4*)(Wq + (size_t)c * 256);
    const float4* rk4 = (const float4*)(Wk + (size_t)c * 256);
    const float4* pl4 = (const float4*)(pet + jx * 264);  // k <  128: x-coord
    const float4* ph4 = (const float4*)(pet + iy * 264);  // k >= 128: y-coord
    float aq = bq[c], ak = bk[c];
    #pragma unroll 8
    for (int t = 0; t < 32; ++t) {
        float4 pv = pl4[t], wq = rq4[t], wk = rk4[t];
        aq += pv.x * wq.x + pv.y * wq.y + pv.z * wq.z + pv.w * wq.w;
        ak += pv.x * wk.x + pv.y * wk.y + pv.z * wk.z + pv.w * wk.w;
    }
    #pragma unroll 8
    for (int t = 0; t < 32; ++t) {
        // pet entries 0..127 repeat 128..255 (same (k&63),(k&64) pattern)
        float4 pv = ph4[t], wq = rq4[32 + t], wk = rk4[32 + t];
        aq += pv.x * wq.x + pv.y * wq.y + pv.z * wq.z + pv.w * wq.w;
        ak += pv.x * wk.x + pv.y * wk.y + pv.z * wk.z + pv.w * wk.w;
    }
    qpeT[c * 64 + p] = aq;
    kpeT[c * 64 + p] = ak;
}

// ---------------------------------------------------------------------------
// Fused per-window kernel. LDS 70656 B -> 2 blocks/CU (16 waves).
// Register-resident attention: no scr scratch, no LDS fences.
// Frag trick: MFMA pairs A-elem(quad,e) with B-elem(quad,e); any k-permutation
// applied to BOTH operands cancels. q/k frags use d=(e>>2)*16+quad*4+(e&3);
// PV pairs P^T (regs) with V read at token offsets quad*4 / 16+quad*4.
#define STRX 264
#define STRV 72
#define VSOFF 16896   // ushorts: xs = [64][264]

__global__ __launch_bounds__(512, 4) void fused_attn(
    const float* __restrict__ x,
    const unsigned short* __restrict__ Wall,   // [q|k|v|p] bf16, 65536 each
    const float* __restrict__ bv,
    const float* __restrict__ qpeT,            // [256][64] fp32 (ch-major)
    const float* __restrict__ kpeT,
    const float* __restrict__ bp,
    float* __restrict__ out)
{
    __shared__ unsigned short sm[35328];       // 70656 B
    unsigned short* xs = sm;                   // [64][264]   (P0-P2, P5? no)
    unsigned short* vs = sm + VSOFF;           // [256][72]   (P1-PV)
    unsigned short* os = sm + VSOFF;           // [64][264]   overlays vs (P4-P5)

    const int tid  = threadIdx.x;
    const int w    = tid >> 6;      // wave 0..7 == head
    const int lane = tid & 63;
    const int quad = lane >> 4;
    const int l15  = lane & 15;

    const int g = blockIdx.x;                  // window 0..2047
    const int b = g >> 8, wy = (g >> 4) & 15, wx = g & 15;
    const int rowbase = b * 16384 + wy * 1024 + wx * 8;

    const f32x4 zero4 = {0.f, 0.f, 0.f, 0.f};

    // ---- P0: stage x window as bf16 into xs ------------------------------
    {
        const int tk = tid >> 3;               // token 0..63
        const int c0 = (tid & 7) * 32;
        const int gr = rowbase + (tk >> 3) * 128 + (tk & 7);
        const float* xr = x + (size_t)gr * 256 + c0;
        #pragma unroll
        for (int i = 0; i < 32; i += 8) {
            float4 f0 = *(const float4*)(xr + i);
            float4 f1 = *(const float4*)(xr + i + 4);
            alignas(16) unsigned short st[8] = {
                f2bf(f0.x), f2bf(f0.y), f2bf(f0.z), f2bf(f0.w),
                f2bf(f1.x), f2bf(f1.y), f2bf(f1.z), f2bf(f1.w)};
            *(uint4*)&xs[tk * STRX + c0 + i] = *(const uint4*)st;
        }
    }
    __syncthreads();

    // ---- P1: V = x @ Wv^T; vT into vs[ch][tok], b64 writes ---------------
    // Swapped operands: D[tok-part][ch=l15] so r spans tokens (contiguous).
    {
        const unsigned short* Wv = Wall + 131072;
        f32x4 acc[4][2];
        #pragma unroll
        for (int i = 0; i < 4; ++i) { acc[i][0] = zero4; acc[i][1] = zero4; }
        #pragma unroll 2
        for (int k0 = 0; k0 < 256; k0 += 32) {
            bf16x8 af[4], wv[2];
            #pragma unroll
            for (int i = 0; i < 4; ++i)
                af[i] = *(const bf16x8*)&xs[(i * 16 + l15) * STRX + k0 + quad * 8];
            #pragma unroll
            for (int j = 0; j < 2; ++j)
                wv[j] = *(const bf16x8*)&Wv[(size_t)(w * 32 + j * 16 + l15) * 256 + k0 + quad * 8];
            #pragma unroll
            for (int i = 0; i < 4; ++i)
                #pragma unroll
                for (int j = 0; j < 2; ++j)
                    acc[i][j] = MFMA16(af[i], wv[j], acc[i][j]);
        }
        #pragma unroll
        for (int j = 0; j < 2; ++j) {
            const int ch = w * 32 + j * 16 + l15;
            const float bbv = bv[ch];
            #pragma unroll
            for (int i = 0; i < 4; ++i) {
                alignas(8) unsigned short t4[4];
                #pragma unroll
                for (int r = 0; r < 4; ++r) t4[r] = f2bf(acc[i][j][r] + bbv);
                *(uint2*)&vs[ch * STRV + i * 16 + quad * 4] = *(const uint2*)t4;
            }
        }
    }
    // no barrier: vs rows are wave-private; same-wave DS ops are in-order

    // ---- P2: qT,kT = Wq/Wk @ x^T -> D[ch-part][tok=l15] (registers) ------
    f32x4 aq[4][2], ak[4][2];   // [tok tile i][ch tile j]
    {
        const unsigned short* Wq = Wall;
        const unsigned short* Wk = Wall + 65536;
        #pragma unroll
        for (int i = 0; i < 4; ++i)
            #pragma unroll
            for (int j = 0; j < 2; ++j) { aq[i][j] = zero4; ak[i][j] = zero4; }
        #pragma unroll 2
        for (int k0 = 0; k0 < 256; k0 += 32) {
            bf16x8 af[4], wq[2], wk[2];
            #pragma unroll
            for (int i = 0; i < 4; ++i)
                af[i] = *(const bf16x8*)&xs[(i * 16 + l15) * STRX + k0 + quad * 8];
            #pragma unroll
            for (int j = 0; j < 2; ++j) {
                wq[j] = *(const bf16x8*)&Wq[(size_t)(w * 32 + j * 16 + l15) * 256 + k0 + quad * 8];
                wk[j] = *(const bf16x8*)&Wk[(size_t)(w * 32 + j * 16 + l15) * 256 + k0 + quad * 8];
            }
            #pragma unroll
            for (int i = 0; i < 4; ++i)
                #pragma unroll
                for (int j = 0; j < 2; ++j) {
                    aq[i][j] = MFMA16(wq[j], af[i], aq[i][j]);
                    ak[i][j] = MFMA16(wk[j], af[i], ak[i][j]);
                }
        }
    }

    // ---- P3: attention, fully register-resident --------------------------
    f32x4 oaT[2][4];            // [ch tile nv][tok tile mt] = O^T
    {
        // PE add + pack fq/fk in registers.
        // frag elem e of lane(quad) holds d = (e>>2)*16 + quad*4 + (e&3);
        // identical permutation on fq and fk -> QK^T exact.
        const float* qb = qpeT + (size_t)(w * 32 + quad * 4) * 64 + l15;
        const float* kb = kpeT + (size_t)(w * 32 + quad * 4) * 64 + l15;
        bf16x8 fq[4], fk[4];
        #pragma unroll
        for (int i = 0; i < 4; ++i) {
            alignas(16) unsigned short tq[8], tk8[8];
            #pragma unroll
            for (int e = 0; e < 8; ++e) {
                const int j = e >> 2, r = e & 3;
                const int off = (j * 16 + r) * 64 + i * 16;
                tq[e]  = f2bf(aq[i][j][r] + qb[off]);
                tk8[e] = f2bf(ak[i][j][r] + kb[off]);
            }
            fq[i] = *(const bf16x8*)tq;
            fk[i] = *(const bf16x8*)tk8;
        }

        // S^T = K·Q^T: s[pt][mt][r] = S[m = mt*16+l15][p = pt*16+quad*4+r]
        f32x4 s[4][4];
        #pragma unroll
        for (int pt = 0; pt < 4; ++pt)
            #pragma unroll
            for (int mt = 0; mt < 4; ++mt)
                s[pt][mt] = MFMA16(fk[pt], fq[mt], zero4);

        // softmax over p: 16 in-reg values per row + 2 cross-lane shuffles
        const float KF = 0.17677669529663687f * 1.4426950408889634f;  // scale*log2e
        #pragma unroll
        for (int mt = 0; mt < 4; ++mt) {
            float mx = s[0][mt][0];
            #pragma unroll
            for (int pt = 0; pt < 4; ++pt)
                #pragma unroll
                for (int r = 0; r < 4; ++r) mx = fmaxf(mx, s[pt][mt][r]);
            mx = fmaxf(mx, __shfl_xor(mx, 16));
            mx = fmaxf(mx, __shfl_xor(mx, 32));
            float sum = 0.f;
            #pragma unroll
            for (int pt = 0; pt < 4; ++pt)
                #pragma unroll
                for (int r = 0; r < 4; ++r) {
                    float e = exp2f((s[pt][mt][r] - mx) * KF);
                    s[pt][mt][r] = e;
                    sum += e;
                }
            sum += __shfl_xor(sum, 16);
            sum += __shfl_xor(sum, 32);
            const float inv = 1.0f / sum;
            #pragma unroll
            for (int pt = 0; pt < 4; ++pt)
                #pragma unroll
                for (int r = 0; r < 4; ++r) s[pt][mt][r] *= inv;
        }

        // PV: O^T = V^T·P. P^T packed from regs (B-frag, perm p);
        // V A-frag read with matching perm: tokens quad*4 and 16+quad*4.
        #pragma unroll
        for (int nv = 0; nv < 2; ++nv)
            #pragma unroll
            for (int mt = 0; mt < 4; ++mt) oaT[nv][mt] = zero4;
        #pragma unroll
        for (int kt = 0; kt < 2; ++kt) {
            bf16x8 pf[4], vf[2];
            #pragma unroll
            for (int mt = 0; mt < 4; ++mt) {
                alignas(16) unsigned short t8[8];
                #pragma unroll
                for (int e = 0; e < 8; ++e)
                    t8[e] = f2bf(s[kt * 2 + (e >> 2)][mt][e & 3]);
                pf[mt] = *(const bf16x8*)t8;
            }
            #pragma unroll
            for (int nv = 0; nv < 2; ++nv) {
                const int c = w * 32 + nv * 16 + l15;
                alignas(16) unsigned short t8[8];
                *(uint2*)&t8[0] = *(const uint2*)&vs[c * STRV + kt * 32 + quad * 4];
                *(uint2*)&t8[4] = *(const uint2*)&vs[c * STRV + kt * 32 + 16 + quad * 4];
                vf[nv] = *(const bf16x8*)t8;
            }
            #pragma unroll
            for (int nv = 0; nv < 2; ++nv)
                #pragma unroll
                for (int mt = 0; mt < 4; ++mt)
                    oaT[nv][mt] = MFMA16(vf[nv], pf[mt], oaT[nv][mt]);
        }
    }
    __syncthreads();   // all PV reads of vs done -> os may overwrite region B

    // ---- P4: O -> os[m][c], b64 writes (r spans contiguous channels) -----
    #pragma unroll
    for (int mt = 0; mt < 4; ++mt)
        #pragma unroll
        for (int nv = 0; nv < 2; ++nv) {
            alignas(8) unsigned short t4[4];
            #pragma unroll
            for (int r = 0; r < 4; ++r) t4[r] = f2bf(oaT[nv][mt][r]);
            *(uint2*)&os[(mt * 16 + l15) * STRX + w * 32 + nv * 16 + quad * 4] = *(const uint2*)t4;
        }
    __syncthreads();

    // ---- P5: out = o @ Wp^T + bp (fp32 to global) ------------------------
    {
        const unsigned short* Wp = Wall + 196608;
        f32x4 ac[4][2];
        #pragma unroll
        for (int i = 0; i < 4; ++i) { ac[i][0] = zero4; ac[i][1] = zero4; }
        #pragma unroll 2
        for (int k0 = 0; k0 < 256; k0 += 32) {
            bf16x8 af[4], bb[2];
            #pragma unroll
            for (int i = 0; i < 4; ++i)
                af[i] = *(const bf16x8*)&os[(i * 16 + l15) * STRX + k0 + quad * 8];
            #pragma unroll
            for (int j = 0; j < 2; ++j)
                bb[j] = *(const bf16x8*)&Wp[(size_t)(w * 32 + j * 16 + l15) * 256 + k0 + quad * 8];
            #pragma unroll
            for (int i = 0; i < 4; ++i)
                #pragma unroll
                for (int j = 0; j < 2; ++j)
                    ac[i][j] = MFMA16(af[i], bb[j], ac[i][j]);
        }
        #pragma unroll
        for (int j = 0; j < 2; ++j) {
            const int n = w * 32 + j * 16 + l15;
            const float bbp = bp[n];
            #pragma unroll
            for (int i = 0; i < 4; ++i) {
                #pragma unroll
                for (int r = 0; r < 4; ++r) {
                    const int m = i * 16 + quad * 4 + r;
                    const int gr = rowbase + (m >> 3) * 128 + (m & 7);
                    out[(size_t)gr * 256 + n] = ac[i][j][r] + bbp;
                }
            }
        }
    }
}

// ---------------------------------------------------------------------------
extern "C" void kernel_launch(void* const* d_in, const int* in_sizes, int n_in,
                              void* d_out, int out_size, void* d_ws, size_t ws_size,
                              hipStream_t stream) {
    const float* x  = (const float*)d_in[0];
    const float* Wq = (const float*)d_in[1];
    const float* bq = (const float*)d_in[2];
    const float* Wk = (const float*)d_in[3];
    const float* bk = (const float*)d_in[4];
    const float* Wv = (const float*)d_in[5];
    const float* bv = (const float*)d_in[6];
    const float* Wp = (const float*)d_in[7];
    const float* bp = (const float*)d_in[8];
    float* out = (float*)d_out;

    char* ws = (char*)d_ws;
    unsigned short* Wbf = (unsigned short*)ws;          // 512 KB bf16 weights
    float* qpeT = (float*)(ws + 524288);                // 64 KB [256][64]
    float* kpeT = (float*)(ws + 524288 + 65536);        // 64 KB [256][64]

    prep<<<256, 256, 0, stream>>>(Wq, bq, Wk, bk, Wv, Wp, Wbf, qpeT, kpeT);
    fused_attn<<<2048, 512, 0, stream>>>(x, Wbf, bv, qpeT, kpeT, bp, out);
}